// Round 2
// baseline (216.124 us; speedup 1.0000x reference)
//
#include <hip/hip_runtime.h>
#include <math.h>

#define TOKENS 4096
#define DMODEL 768
#define NHEADS 12
#define HDIM   64
#define QKV_N  2304          // 3*DMODEL
#define ATTN_SCALE 0.125f    // HDIM^-0.5
// fold log2(e) into Q so softmax uses v_exp_f32 (2^x) directly
#define QSCALE_LOG2E (0.125f * 1.44269504088896340736f)

typedef __attribute__((ext_vector_type(8))) short bf16x8;   // 8 bf16 = 4 VGPRs
typedef __attribute__((ext_vector_type(4))) float floatx4;

__device__ __forceinline__ ushort f2bf(float f) {
    union { float f; unsigned u; } cv; cv.f = f;
    unsigned u = cv.u;
    u += 0x7fffu + ((u >> 16) & 1u);   // round-to-nearest-even
    return (ushort)(u >> 16);
}

// pack two fp32 -> two bf16 (RNE) in one dword via v_cvt_pk_bf16_f32
__device__ __forceinline__ unsigned cvt_pk_bf16(float a, float b) {
    unsigned r;
    asm("v_cvt_pk_bf16_f32 %0, %1, %2" : "=v"(r) : "v"(a), "v"(b));
    return r;
}

// async 16B global->LDS (lane i lands at ldsbase + i*16)
__device__ __forceinline__ void gl2lds16(const ushort* g, ushort* l) {
    __builtin_amdgcn_global_load_lds(
        (const __attribute__((address_space(1))) void*)g,
        (__attribute__((address_space(3))) void*)l, 16, 0, 0);
}

// fragment read (64-ushort rows): logical chunk c of row r at phys (c ^ (r&7))
__device__ __forceinline__ bf16x8 frag(const ushort* ls, int row, int chunk) {
    return *(const bf16x8*)(ls + row * 64 + ((chunk ^ (row & 7)) * 8));
}

// ---------------------------------------------------------------------------
// fp32 -> bf16 elementwise (x)
// ---------------------------------------------------------------------------
__global__ __launch_bounds__(256) void cvt_bf16_kernel(
    const float* __restrict__ in, ushort* __restrict__ out, int n4)
{
    const int i = blockIdx.x * 256 + threadIdx.x;
    if (i < n4) {
        const float4 v = ((const float4*)in)[i];
        ushort4 h;
        h.x = f2bf(v.x); h.y = f2bf(v.y); h.z = f2bf(v.z); h.w = f2bf(v.w);
        ((ushort4*)out)[i] = h;
    }
}

// ---------------------------------------------------------------------------
// fp32 [R][C] -> bf16 [C][R] transpose-convert (weights -> B^T operand layout)
// ---------------------------------------------------------------------------
__global__ __launch_bounds__(256) void transpose_cvt_kernel(
    const float* __restrict__ in, ushort* __restrict__ out, int R, int C)
{
    __shared__ ushort tile[32][33];
    const int tx  = threadIdx.x & 31;
    const int ty8 = threadIdx.x >> 5;           // 0..7
    const int c0 = blockIdx.x * 32;
    const int r0 = blockIdx.y * 32;
    #pragma unroll
    for (int p = 0; p < 4; ++p) {
        const int r = ty8 + p * 8;
        tile[r][tx] = f2bf(in[(size_t)(r0 + r) * C + c0 + tx]);
    }
    __syncthreads();
    #pragma unroll
    for (int p = 0; p < 4; ++p) {
        const int c = ty8 + p * 8;
        out[(size_t)(c0 + c) * R + r0 + tx] = tile[tx][c];
    }
}

// ---------------------------------------------------------------------------
// MFMA GEMM body (m97 recipe): 128 x (NT*32) tile, BK=64, 4 waves 2x2.
// ---------------------------------------------------------------------------
template<int NT>
__device__ __forceinline__ void gemm_body_async(
    const ushort* __restrict__ A, const ushort* __restrict__ Bt, int K,
    int m0, int n0, floatx4 acc[4][NT], ushort* ls)
{
    ushort* lsA = ls;
    ushort* lsB = ls + 8192;

    const int tid  = threadIdx.x;
    const int lane = tid & 63;
    const int wave = tid >> 6;
    const int wm = wave >> 1, wn = wave & 1;
    const int quad = lane >> 4, l16 = lane & 15;

    const int lrow = lane >> 3;          // 0..7
    const int csw  = ((lane & 7) ^ lrow) * 8;   // swizzled global chunk (ushorts)

    const ushort* gA = A  + (size_t)(m0 + wave * 32 + lrow) * K + csw;
    const ushort* gB = Bt + (size_t)(n0 + wave * NT * 8 + lrow) * K + csw;
    ushort* lA = lsA + (wave * 32) * 64;
    ushort* lB = lsB + (wave * NT * 8) * 64;

    for (int k0 = 0; k0 < K; k0 += 64) {
        __syncthreads();
        #pragma unroll
        for (int p = 0; p < 4; ++p)
            gl2lds16(gA + (size_t)p * 8 * K + k0, lA + p * 8 * 64);
        #pragma unroll
        for (int p = 0; p < NT; ++p)
            gl2lds16(gB + (size_t)p * 8 * K + k0, lB + p * 8 * 64);
        __syncthreads();

        #pragma unroll
        for (int ks = 0; ks < 2; ++ks) {
            bf16x8 af[4], bfr[NT];
            #pragma unroll
            for (int mt = 0; mt < 4; ++mt)
                af[mt] = frag(lsA, wm * 64 + mt * 16 + l16, ks * 4 + quad);
            #pragma unroll
            for (int nt = 0; nt < NT; ++nt)
                bfr[nt] = frag(lsB, wn * NT * 16 + nt * 16 + l16, ks * 4 + quad);
            #pragma unroll
            for (int mt = 0; mt < 4; ++mt)
                #pragma unroll
                for (int nt = 0; nt < NT; ++nt)
                    acc[mt][nt] = __builtin_amdgcn_mfma_f32_16x16x32_bf16(
                        af[mt], bfr[nt], acc[mt][nt], 0, 0, 0);
        }
    }
}

// ---------------------------------------------------------------------------
// qkv GEMM: 128x128 tiles. Epilogue re-tiles through LDS (stride 136).
// ---------------------------------------------------------------------------
__global__ __launch_bounds__(256) void gemm_qkv_mfma(
    const ushort* __restrict__ Xb, const ushort* __restrict__ Wt,
    ushort* __restrict__ Qb, ushort* __restrict__ Kb, ushort* __restrict__ Vt)
{
    __shared__ __align__(16) ushort ls[16384];   // 32 KB: GEMM tiles + retile
    const int m0 = blockIdx.y * 128;
    const int n0 = blockIdx.x * 128;

    floatx4 acc[4][4] = {};
    gemm_body_async<4>(Xb, Wt, DMODEL, m0, n0, acc, ls);

    const int tid  = threadIdx.x;
    const int lane = tid & 63;
    const int wave = tid >> 6;
    const int wm = wave >> 1, wn = wave & 1;
    const int quad = lane >> 4, l16 = lane & 15;

    if (n0 < 2 * DMODEL) {
        // ---- Q or K: two passes over 64-row halves ----
        const float scale = (n0 < DMODEL) ? QSCALE_LOG2E : 1.0f;
        ushort* outp = (n0 < DMODEL) ? Qb : Kb;
        const int colg = (n0 < DMODEL) ? n0 : n0 - DMODEL;
        #pragma unroll
        for (int p = 0; p < 2; ++p) {
            __syncthreads();
            if (wm == p) {
                #pragma unroll
                for (int mt = 0; mt < 4; ++mt)
                    #pragma unroll
                    for (int nt = 0; nt < 4; ++nt) {
                        const int row = mt * 16 + quad * 4;
                        const int col = wn * 64 + nt * 16 + l16;
                        #pragma unroll
                        for (int r = 0; r < 4; ++r)
                            ls[(row + r) * 136 + col] = f2bf(acc[mt][nt][r] * scale);
                    }
            }
            __syncthreads();
            #pragma unroll
            for (int p2 = 0; p2 < 4; ++p2) {
                const int row = (tid >> 4) + p2 * 16;
                const int c8  = (tid & 15) * 8;
                *(uint4*)(outp + (size_t)(m0 + p * 64 + row) * DMODEL + colg + c8) =
                    *(const uint4*)(ls + row * 136 + c8);
            }
        }
    } else {
        // ---- V transposed: two passes over 64-hd halves ----
        const int hd0 = n0 - 2 * DMODEL;
        #pragma unroll
        for (int p = 0; p < 2; ++p) {
            __syncthreads();
            if (wn == p) {
                #pragma unroll
                for (int mt = 0; mt < 4; ++mt)
                    #pragma unroll
                    for (int nt = 0; nt < 4; ++nt) {
                        const int hd  = nt * 16 + l16;
                        const int tok = wm * 64 + mt * 16 + quad * 4;
                        #pragma unroll
                        for (int r = 0; r < 4; ++r)
                            ls[hd * 136 + tok + r] = f2bf(acc[mt][nt][r]);
                    }
            }
            __syncthreads();
            #pragma unroll
            for (int p2 = 0; p2 < 4; ++p2) {
                const int row = (tid >> 4) + p2 * 16;    // local hd
                const int c8  = (tid & 15) * 8;          // token chunk
                *(uint4*)(Vt + (size_t)(hd0 + p * 64 + row) * TOKENS + m0 + c8) =
                    *(const uint4*)(ls + row * 136 + c8);
            }
        }
    }
}

// ---------------------------------------------------------------------------
// proj GEMM: 128x64 tiles (grid 384), direct fp32 stores (full 64B sectors).
// ---------------------------------------------------------------------------
__global__ __launch_bounds__(256) void gemm_proj_mfma(
    const ushort* __restrict__ Ab, const ushort* __restrict__ Wt,
    const float* __restrict__ bias, float* __restrict__ out)
{
    __shared__ __align__(16) ushort ls[12288];   // 16 KB A + 8 KB B
    const int m0 = blockIdx.y * 128;
    const int n0 = blockIdx.x * 64;

    floatx4 acc[4][2] = {};
    gemm_body_async<2>(Ab, Wt, DMODEL, m0, n0, acc, ls);

    const int lane = threadIdx.x & 63;
    const int wave = threadIdx.x >> 6;
    const int wm = wave >> 1, wn = wave & 1;
    const int quad = lane >> 4, l16 = lane & 15;
    const int row0 = m0 + wm * 64 + quad * 4;
    const int col0 = n0 + wn * 32;

    #pragma unroll
    for (int nt = 0; nt < 2; ++nt) {
        const int col = col0 + nt * 16 + l16;
        const float bv = bias[col];
        #pragma unroll
        for (int mt = 0; mt < 4; ++mt)
            #pragma unroll
            for (int r = 0; r < 4; ++r)
                out[(size_t)(row0 + mt * 16 + r) * DMODEL + col] =
                    acc[mt][nt][r] + bv;
    }
}

// ---------------------------------------------------------------------------
// MFMA flash attention v3 — KEY-SPLIT waves (kills the 4x LDS amplification).
//
// Per 128-key chunk, wave w owns keys [w*32, w*32+32) and computes partial
// O/l for ALL 64 queries (Q register-resident, 4 q-tiles). Per-wave LDS
// reads = exactly its own K (4 b128) + V (8 b64) slice: 8 KB/wave/chunk vs
// 16 KB/wave per 64 keys before (4x less traffic). P stays fully in-register
// via the proven permuted k-slot mapping (k-slots quad*8+{0..3} <- key-subtile
// 0 keys quad*4+{0..3}; +{4..7} <- subtile 1), matched by b64 V reads.
//
// LDS: K [128 key][64 hd] rows, 3-bit XOR slot swizzle (c ^ (row&7));
//      V [64 hd][128 tok] rows, 4-bit XOR slot swizzle (t ^ (hd&15)).
// Both read patterns have perfectly balanced bank classes (8 lanes per
// 16B-class, 4 per 8B-class) => conflict-free. DMA dests stay linear;
// swizzle applied on the per-lane GLOBAL source address (rule #21).
//
// Epilogue: waves 1-3 write partial O (f32, stride-66 rows => 2-way max)
// + l to LDS; wave 0 reduces and stores. Once per block (~3% overhead).
// ---------------------------------------------------------------------------
__global__ __launch_bounds__(256, 2) void attn_mfma_kernel(
    const ushort* __restrict__ Qb, const ushort* __restrict__ Kb,
    const ushort* __restrict__ Vt, ushort* __restrict__ attn_out)
{
    // ushort units: K0 @0 (128x64), K1 @8192, V0 @16384 (64x128), V1 @24576
    __shared__ __align__(16) ushort lds[32768];   // 64 KB

    const int tid  = threadIdx.x;
    const int wave = tid >> 6;
    const int lane = tid & 63;
    const int quad = lane >> 4;
    const int l16  = lane & 15;
    const int h    = blockIdx.y;
    const int i0   = blockIdx.x * 64;

    // Q fragments: all 4 q-tiles, register-resident (B-operand: col=l16=q row)
    bf16x8 qf[4][2];
    #pragma unroll
    for (int jt = 0; jt < 4; ++jt) {
        const ushort* qb = Qb + (size_t)(i0 + jt * 16 + l16) * DMODEL + h * HDIM;
        qf[jt][0] = *(const bf16x8*)(qb + quad * 8);
        qf[jt][1] = *(const bf16x8*)(qb + 32 + quad * 8);
    }

    bf16x8 ones;
    #pragma unroll
    for (int i = 0; i < 8; ++i) ones[i] = (short)0x3F80;   // bf16 1.0

    floatx4 O[4][4] = {};    // [q-tile][d-tile], partial over this wave's keys
    floatx4 Ol[4]   = {};    // [q-tile] partial row-sums

    // staging address math
    const int lrow8 = lane >> 3;                    // 0..7
    const int csw8  = ((lane & 7) ^ lrow8) * 8;     // K: 3-bit XOR on global chunk
    const ushort* gK = Kb + (size_t)(wave * 32 + lrow8) * DMODEL + h * HDIM + csw8;
    const int l4 = lane >> 4;                       // 0..3
    const ushort* gVrow = Vt + (size_t)(h * HDIM + wave * 16 + l4) * TOKENS;

    // prologue: stage chunk 0 into buffer 0
    #pragma unroll
    for (int p = 0; p < 4; ++p)
        gl2lds16(gK + (size_t)p * 8 * DMODEL, lds + (wave * 32 + p * 8) * 64);
    #pragma unroll
    for (int p = 0; p < 4; ++p) {
        const int vsw = ((lane & 15) ^ (p * 4 + l4)) * 8;   // 4-bit XOR slot swizzle
        gl2lds16(gVrow + (size_t)(p * 4) * TOKENS + vsw,
                 lds + 16384 + (wave * 16 + p * 4) * 128);
    }

    for (int j0 = 0; j0 < TOKENS; j0 += 128) {
        const int cur = (j0 >> 7) & 1;
        const ushort* Ks = lds + cur * 8192;
        const ushort* Vs = lds + 16384 + cur * 8192;
        ushort* Kn = lds + (1 - cur) * 8192;
        ushort* Vn = lds + 16384 + (1 - cur) * 8192;

        __syncthreads();   // buf[cur] DMA complete; all waves done reading spare

        if (j0 + 128 < TOKENS) {   // prefetch next chunk into the spare buffer
            #pragma unroll
            for (int p = 0; p < 4; ++p)
                gl2lds16(gK + (size_t)(j0 + 128) * DMODEL + (size_t)p * 8 * DMODEL,
                         Kn + (wave * 32 + p * 8) * 64);
            #pragma unroll
            for (int p = 0; p < 4; ++p) {
                const int vsw = ((lane & 15) ^ (p * 4 + l4)) * 8;
                gl2lds16(gVrow + (size_t)(p * 4) * TOKENS + (j0 + 128) + vsw,
                         Vn + (wave * 16 + p * 4) * 128);
            }
        }

        // ---- own-slice K frags + V frags (issue all LDS reads up front) ----
        bf16x8 af[2][2];
        #pragma unroll
        for (int ks2 = 0; ks2 < 2; ++ks2)
            #pragma unroll
            for (int kh = 0; kh < 2; ++kh)
                af[ks2][kh] = frag(Ks, wave * 32 + ks2 * 16 + l16, kh * 4 + quad);

        bf16x8 vf[4];
        #pragma unroll
        for (int nt = 0; nt < 4; ++nt) {
            const int vrow = nt * 16 + l16;
            union { bf16x8 v; uint2 d[2]; } vu;
            #pragma unroll
            for (int ks2 = 0; ks2 < 2; ++ks2) {
                const int t   = wave * 4 + ks2 * 2 + (quad >> 1);   // logical 16B slot
                const int pos = t ^ (vrow & 15);                    // physical slot
                vu.d[ks2] = *(const uint2*)(Vs + vrow * 128 + pos * 8 + (quad & 1) * 4);
            }
            vf[nt] = vu.v;
        }

        // ---- S^T = K * Q^T over own 32-key slice (log2-domain scores) ----
        floatx4 Sv[4][2];
        #pragma unroll
        for (int jt = 0; jt < 4; ++jt)
            #pragma unroll
            for (int ks2 = 0; ks2 < 2; ++ks2) {
                floatx4 s = {0.f, 0.f, 0.f, 0.f};
                s = __builtin_amdgcn_mfma_f32_16x16x32_bf16(af[ks2][0], qf[jt][0], s, 0, 0, 0);
                s = __builtin_amdgcn_mfma_f32_16x16x32_bf16(af[ks2][1], qf[jt][1], s, 0, 0, 0);
                Sv[jt][ks2] = s;
            }

        // ---- p = 2^s, pack in-register; l += P*1 ----
        bf16x8 pa[4];
        #pragma unroll
        for (int jt = 0; jt < 4; ++jt) {
            union { bf16x8 v; unsigned u[4]; } pu;
            #pragma unroll
            for (int ks2 = 0; ks2 < 2; ++ks2) {
                const float p0 = __builtin_amdgcn_exp2f(Sv[jt][ks2][0]);
                const float p1 = __builtin_amdgcn_exp2f(Sv[jt][ks2][1]);
                const float p2 = __builtin_amdgcn_exp2f(Sv[jt][ks2][2]);
                const float p3 = __builtin_amdgcn_exp2f(Sv[jt][ks2][3]);
                pu.u[ks2 * 2]     = cvt_pk_bf16(p0, p1);
                pu.u[ks2 * 2 + 1] = cvt_pk_bf16(p2, p3);
            }
            pa[jt] = pu.v;
            Ol[jt] = __builtin_amdgcn_mfma_f32_16x16x32_bf16(pa[jt], ones, Ol[jt], 0, 0, 0);
        }

        // ---- O += P * V (16 independent mfma) ----
        #pragma unroll
        for (int jt = 0; jt < 4; ++jt)
            #pragma unroll
            for (int nt = 0; nt < 4; ++nt)
                O[jt][nt] = __builtin_amdgcn_mfma_f32_16x16x32_bf16(
                    pa[jt], vf[nt], O[jt][nt], 0, 0, 0);
    }

    // ---- cross-wave reduction + store ----
    __syncthreads();                       // all compute done, LDS reusable
    float* Of  = (float*)lds;              // 3 regions of [64][66] f32
    float* Olf = ((float*)lds) + 3 * 64 * 66;   // 3 x [64] f32
    if (wave != 0) {
        const int rg = (wave - 1) * 64 * 66;
        #pragma unroll
        for (int jt = 0; jt < 4; ++jt) {
            #pragma unroll
            for (int nt = 0; nt < 4; ++nt)
                #pragma unroll
                for (int r = 0; r < 4; ++r)
                    Of[rg + (jt * 16 + quad * 4 + r) * 66 + nt * 16 + l16] = O[jt][nt][r];
            if (l16 == 0) {
                #pragma unroll
                for (int r = 0; r < 4; ++r)
                    Olf[(wave - 1) * 64 + jt * 16 + quad * 4 + r] = Ol[jt][r];
            }
        }
    }
    __syncthreads();
    if (wave == 0) {
        #pragma unroll
        for (int jt = 0; jt < 4; ++jt) {
            const int qr = jt * 16 + quad * 4;
            float linv[4];
            #pragma unroll
            for (int r = 0; r < 4; ++r) {
                const float l = Ol[jt][r] + Olf[qr + r] + Olf[64 + qr + r]
                              + Olf[128 + qr + r];
                linv[r] = __builtin_amdgcn_rcpf(l);
            }
            #pragma unroll
            for (int nt = 0; nt < 4; ++nt) {
                const int d = h * HDIM + nt * 16 + l16;
                #pragma unroll
                for (int r = 0; r < 4; ++r) {
                    const float o = O[jt][nt][r]
                        + Of[(qr + r) * 66 + nt * 16 + l16]
                        + Of[64 * 66 + (qr + r) * 66 + nt * 16 + l16]
                        + Of[2 * 64 * 66 + (qr + r) * 66 + nt * 16 + l16];
                    attn_out[(size_t)(i0 + qr + r) * DMODEL + d] = f2bf(o * linv[r]);
                }
            }
        }
    }
}

// ---------------------------------------------------------------------------
extern "C" void kernel_launch(void* const* d_in, const int* in_sizes, int n_in,
                              void* d_out, int out_size, void* d_ws, size_t ws_size,
                              hipStream_t stream)
{
    const float* x     = (const float*)d_in[0];
    const float* Wqkv  = (const float*)d_in[1];
    const float* Wproj = (const float*)d_in[2];
    const float* bproj = (const float*)d_in[3];
    float* out = (float*)d_out;

    ushort* Xb     = (ushort*)d_ws;                          // [4096][768]
    ushort* WqkvT  = Xb    + (size_t)TOKENS * DMODEL;        // [2304][768]
    ushort* WprojT = WqkvT + (size_t)QKV_N * DMODEL;         // [768][768]
    ushort* Qb     = WprojT + (size_t)DMODEL * DMODEL;       // [4096][768]
    ushort* Kb     = Qb    + (size_t)TOKENS * DMODEL;        // [4096][768]
    ushort* Vt     = Kb    + (size_t)TOKENS * DMODEL;        // [768][4096]
    ushort* attn   = Vt    + (size_t)TOKENS * DMODEL;        // [4096][768]

    cvt_bf16_kernel<<<dim3(TOKENS * DMODEL / 4 / 256), 256, 0, stream>>>(
        x, Xb, TOKENS * DMODEL / 4);
    transpose_cvt_kernel<<<dim3(QKV_N / 32, DMODEL / 32), 256, 0, stream>>>(
        Wqkv, WqkvT, DMODEL, QKV_N);
    transpose_cvt_kernel<<<dim3(DMODEL / 32, DMODEL / 32), 256, 0, stream>>>(
        Wproj, WprojT, DMODEL, DMODEL);

    gemm_qkv_mfma<<<dim3(QKV_N / 128, TOKENS / 128), 256, 0, stream>>>(
        Xb, WqkvT, Qb, Kb, Vt);

    attn_mfma_kernel<<<dim3(TOKENS / 64, NHEADS), 256, 0, stream>>>(
        Qb, Kb, Vt, attn);

    gemm_proj_mfma<<<dim3(DMODEL / 64, TOKENS / 128), 256, 0, stream>>>(
        attn, WprojT, bproj, out);
}